// Round 6
// baseline (202.566 us; speedup 1.0000x reference)
//
#include <hip/hip_runtime.h>
#include <hip/hip_cooperative_groups.h>
#include <math.h>

namespace cg = cooperative_groups;

// ---------------------------------------------------------------------------
// AttentiveFPModule: knn(K=3) attentive interpolate + concat + Linear + BN + LeakyReLU
// Sizes: Nx=4096, Ny=16384, C=256, Cs=128, Co=256, B=4, Kin=384
// 3 launches: k_prep, k_knn, k_coop (cooperative: gather->MFMA->BN->write).
// ---------------------------------------------------------------------------

#define KNEI 3
#define GL 16           // lanes per y-point in k_knn
#define UNR 4           // scan unroll
#define CIN 256         // C
#define CSK 128         // Cs
#define CO  256         // Co
#define NKS 12          // Kin / 32
#define NNT 16          // Co / 16
#define NYF 16384.0f
#define NPOS4 12288     // Ny*3/4
#define NTAIL4 16384    // NPOS4 + Ny/4

typedef __attribute__((ext_vector_type(8))) short bf16x8;
typedef __attribute__((ext_vector_type(4))) float f32x4;

__device__ __forceinline__ ushort f2bf(float f) {
    unsigned u = __float_as_uint(f);
    u += 0x7fffu + ((u >> 16) & 1u);
    return (ushort)(u >> 16);
}

__device__ __forceinline__ bool nless(float da, int ia, float db, int ib) {
    return (da < db) || (da == db && ia < ib);
}

__device__ __forceinline__ void ins3f(float dd, int j,
                                      float& d0, int& i0,
                                      float& d1, int& i1,
                                      float& d2, int& i2) {
    bool l0 = dd < d0;
    bool l1 = dd < d1;
    bool l2 = dd < d2;
    float n2 = l1 ? d1 : (l2 ? dd : d2); int m2 = l1 ? i1 : (l2 ? j : i2);
    float n1 = l0 ? d0 : (l1 ? dd : d1); int m1 = l0 ? i0 : (l1 ? j : i1);
    float n0 = l0 ? dd : d0;             int m0 = l0 ? j  : i0;
    d0 = n0; i0 = m0; d1 = n1; i1 = m1; d2 = n2; i2 = m2;
}

__device__ __forceinline__ void ins3t(float dd, int j,
                                      float& d0, int& i0,
                                      float& d1, int& i1,
                                      float& d2, int& i2) {
    bool l0 = nless(dd, j, d0, i0);
    bool l1 = nless(dd, j, d1, i1);
    bool l2 = nless(dd, j, d2, i2);
    float n2 = l1 ? d1 : (l2 ? dd : d2); int m2 = l1 ? i1 : (l2 ? j : i2);
    float n1 = l0 ? d0 : (l1 ? dd : d1); int m1 = l0 ? i0 : (l1 ? j : i1);
    float n0 = l0 ? dd : d0;             int m0 = l0 ? j  : i0;
    d0 = n0; i0 = m0; d1 = n1; i1 = m1; d2 = n2; i2 = m2;
}

// K1 (multi-role by block range): attv/pos4 | W1->Bbuf fragments | start + pad
__global__ void k_prep(const float* __restrict__ x, const float* __restrict__ pos,
                       const float* __restrict__ w_att, const float* __restrict__ W1,
                       const int* __restrict__ batch,
                       float* __restrict__ attv, float4* __restrict__ pos4,
                       uint4* __restrict__ Bbuf, int* __restrict__ start,
                       int Nx, int NB) {
    int nb_x = Nx >> 2;
    int bid = blockIdx.x;
    int wave = threadIdx.x >> 6;
    int lane = threadIdx.x & 63;

    if (bid < nb_x) {
        int wid = bid * 4 + wave;
        float s = 0.f;
        for (int k = lane * 4; k < CIN; k += 256) {
            float4 xv = *reinterpret_cast<const float4*>(x + (size_t)wid * CIN + k);
            float4 wv = *reinterpret_cast<const float4*>(w_att + k);
            s += xv.x * wv.x + xv.y * wv.y + xv.z * wv.z + xv.w * wv.w;
        }
        #pragma unroll
        for (int off = 32; off; off >>= 1) s += __shfl_xor(s, off);
        if (lane == 0) {
            attv[wid] = s;
            float px = pos[wid * 3], py = pos[wid * 3 + 1], pz = pos[wid * 3 + 2];
            pos4[wid] = make_float4(px, py, pz, px * px + py * py + pz * pz);
        }
        return;
    }
    if (bid < nb_x + 48) {
        // B fragment: Bbuf[(ks*16+nt)*64 + lane] = 8 bf16:
        //   elem j = W1[ks*32 + (lane>>4)*8 + j][nt*16 + (lane&15)]
        int p  = (bid - nb_x) * 4 + wave;      // 0..191
        int ks = p >> 4, nt = p & 15;
        int kb = ks * 32 + (lane >> 4) * 8;
        int n  = nt * 16 + (lane & 15);
        ushort u[8];
        #pragma unroll
        for (int j = 0; j < 8; ++j)
            u[j] = f2bf(W1[(size_t)(kb + j) * CO + n]);
        uint4 o;
        o.x = (unsigned)u[0] | ((unsigned)u[1] << 16);
        o.y = (unsigned)u[2] | ((unsigned)u[3] << 16);
        o.z = (unsigned)u[4] | ((unsigned)u[5] << 16);
        o.w = (unsigned)u[6] | ((unsigned)u[7] << 16);
        Bbuf[(size_t)(ks * 16 + nt) * 64 + lane] = o;
        return;
    }
    int t = threadIdx.x;
    if (t < 64) {
        int b = t;
        if (b > NB) return;
        int lo = 0, hi = Nx;
        while (lo < hi) {
            int mid = (lo + hi) >> 1;
            if (batch[mid] < b) lo = mid + 1; else hi = mid;
        }
        start[b] = lo;
    } else if (t < 128) {
        pos4[Nx + (t - 64)] = make_float4(0.f, 0.f, 0.f, 0.f);
    }
}

// K2: GL lanes per y point; 4-wide unrolled branchless scan, two top-3 sets,
// merge + butterfly.
__global__ void k_knn(const float4* __restrict__ pos4,
                      const float* __restrict__ attv,
                      const float* __restrict__ pos_skip,
                      const int* __restrict__ batch_skip,
                      const int* __restrict__ start,
                      int* __restrict__ knn_idx, float* __restrict__ knn_coef,
                      int Ny) {
    int gtid = blockIdx.x * blockDim.x + threadIdx.x;
    int i    = gtid >> 4;
    int sub  = gtid & (GL - 1);
    if (i >= Ny) return;

    float py0 = pos_skip[i * 3], py1 = pos_skip[i * 3 + 1], py2 = pos_skip[i * 3 + 2];
    int bb = batch_skip[i];
    int s = start[bb], e = start[bb + 1];
    float ysq = py0 * py0 + py1 * py1 + py2 * py2;

    const float FBIG = 3.38e38f;
    float a0 = __int_as_float(0x7f800000), a1 = a0, a2 = a0;
    float b0 = a0, b1v = a0, b2 = a0;
    int   ia0 = 0x7fffffff, ia1 = 0x7fffffff, ia2 = 0x7fffffff;
    int   ib0 = 0x7fffffff, ib1 = 0x7fffffff, ib2 = 0x7fffffff;

    for (int jb = s + sub; jb < e; jb += GL * UNR) {
        int j0 = jb, j1 = jb + GL, j2 = jb + 2 * GL, j3 = jb + 3 * GL;
        float4 v0 = pos4[j0];
        float4 v1 = pos4[j1];
        float4 v2 = pos4[j2];
        float4 v3 = pos4[j3];
        float t0 = fmaf(py2, v0.z, fmaf(py1, v0.y, py0 * v0.x));
        float t1 = fmaf(py2, v1.z, fmaf(py1, v1.y, py0 * v1.x));
        float t2 = fmaf(py2, v2.z, fmaf(py1, v2.y, py0 * v2.x));
        float t3 = fmaf(py2, v3.z, fmaf(py1, v3.y, py0 * v3.x));
        float dd0 = fmaf(-2.f, t0, ysq + v0.w);
        float dd1 = fmaf(-2.f, t1, ysq + v1.w);
        float dd2 = fmaf(-2.f, t2, ysq + v2.w);
        float dd3 = fmaf(-2.f, t3, ysq + v3.w);
        dd1 = (j1 < e) ? dd1 : FBIG;
        dd2 = (j2 < e) ? dd2 : FBIG;
        dd3 = (j3 < e) ? dd3 : FBIG;
        ins3f(dd0, j0, a0, ia0, a1, ia1, a2, ia2);
        ins3f(dd1, j1, b0, ib0, b1v, ib1, b2, ib2);
        ins3f(dd2, j2, a0, ia0, a1, ia1, a2, ia2);
        ins3f(dd3, j3, b0, ib0, b1v, ib1, b2, ib2);
    }

    ins3t(b0, ib0, a0, ia0, a1, ia1, a2, ia2);
    ins3t(b1v, ib1, a0, ia0, a1, ia1, a2, ia2);
    ins3t(b2, ib2, a0, ia0, a1, ia1, a2, ia2);

    #pragma unroll
    for (int off = 1; off < GL; off <<= 1) {
        float e0 = __shfl_xor(a0, off), e1 = __shfl_xor(a1, off), e2 = __shfl_xor(a2, off);
        int   j0 = __shfl_xor(ia0, off), j1 = __shfl_xor(ia1, off), j2 = __shfl_xor(ia2, off);
        ins3t(e0, j0, a0, ia0, a1, ia1, a2, ia2);
        ins3t(e1, j1, a0, ia0, a1, ia1, a2, ia2);
        ins3t(e2, j2, a0, ia0, a1, ia1, a2, ia2);
    }

    if (sub == 0) {
        int   jj[3] = { ia0, ia1, ia2 };
        float w[3], a[3];
        #pragma unroll
        for (int t = 0; t < KNEI; ++t) {
            int j = (jj[t] == 0x7fffffff) ? 0 : jj[t];
            jj[t] = j;
            float4 v = pos4[j];
            float dx = v.x - py0;
            float dy = v.y - py1;
            float dz = v.z - py2;
            float sqd = dx * dx + dy * dy + dz * dz;
            w[t] = 1.f / fmaxf(sqd, 1e-16f);
            a[t] = attv[j];
        }
        float m  = fmaxf(a[0], fmaxf(a[1], a[2]));
        float e0s = expf(a[0] - m), e1s = expf(a[1] - m), e2s = expf(a[2] - m);
        float se  = e0s + e1s + e2s;
        float den = w[0] + w[1] + w[2];
        float inv = 1.f / (se * den);
        float c[3] = { w[0] * e0s * inv, w[1] * e1s * inv, w[2] * e2s * inv };
        #pragma unroll
        for (int t = 0; t < KNEI; ++t) {
            knn_idx[i * 3 + t]  = jj[t];
            knn_coef[i * 3 + t] = c[t];
        }
    }
}

// K3 (cooperative, 256 blocks x 256 threads, 1 block/CU):
//   A: gather+combine A=[y||x_skip] into 12 bf16x8 register fragments/lane
//   B: MFMA over 12 k-steps, B double-buffered in LDS; h kept in registers
//   C: grid.sync; block b reduces channel b -> scale/shift; grid.sync
//   D: BN+LeakyReLU on registers -> single h write; tail outputs
__global__ __launch_bounds__(256) void k_coop(
    const float* __restrict__ x, const float* __restrict__ x_skip,
    const uint4* __restrict__ Bbuf, const float* __restrict__ b1,
    const int* __restrict__ knn_idx, const float* __restrict__ knn_coef,
    const float* __restrict__ gamma, const float* __restrict__ beta,
    float* __restrict__ outp, float* __restrict__ psum_t, float* __restrict__ psq_t,
    float* __restrict__ sscale,
    const float4* __restrict__ pos_skip4, const int4* __restrict__ batch4) {
    __shared__ uint4 Bls[2][1024];   // 32 KB
    __shared__ float cred[16];
    const int tid = threadIdx.x;
    const int wave = tid >> 6, lane = tid & 63;
    const int blk = blockIdx.x;
    cg::grid_group grid = cg::this_grid();

    // ---- Phase A: gather A-fragments into registers ----
    const int row16 = lane & 15, kg = lane >> 4;
    const int i = blk * 64 + wave * 16 + row16;
    const int gi0 = knn_idx[i * 3 + 0];
    const int gi1 = knn_idx[i * 3 + 1];
    const int gi2 = knn_idx[i * 3 + 2];
    const float c0 = knn_coef[i * 3 + 0];
    const float c1 = knn_coef[i * 3 + 1];
    const float c2 = knn_coef[i * 3 + 2];

    bf16x8 afrag[NKS];
    #pragma unroll
    for (int ks = 0; ks < 8; ++ks) {
        const int k0 = ks * 32 + kg * 8;
        const float4* p0 = reinterpret_cast<const float4*>(x + (size_t)gi0 * CIN + k0);
        const float4* p1 = reinterpret_cast<const float4*>(x + (size_t)gi1 * CIN + k0);
        const float4* p2 = reinterpret_cast<const float4*>(x + (size_t)gi2 * CIN + k0);
        #pragma unroll
        for (int h = 0; h < 2; ++h) {
            float4 a = p0[h], b = p1[h], c = p2[h];
            float vx = c0 * a.x + c1 * b.x + c2 * c.x;
            float vy = c0 * a.y + c1 * b.y + c2 * c.y;
            float vz = c0 * a.z + c1 * b.z + c2 * c.z;
            float vw = c0 * a.w + c1 * b.w + c2 * c.w;
            afrag[ks][h * 4 + 0] = (short)f2bf(vx);
            afrag[ks][h * 4 + 1] = (short)f2bf(vy);
            afrag[ks][h * 4 + 2] = (short)f2bf(vz);
            afrag[ks][h * 4 + 3] = (short)f2bf(vw);
        }
    }
    #pragma unroll
    for (int ks = 8; ks < NKS; ++ks) {
        const int k0 = (ks - 8) * 32 + kg * 8;
        const float4* ps = reinterpret_cast<const float4*>(x_skip + (size_t)i * CSK + k0);
        #pragma unroll
        for (int h = 0; h < 2; ++h) {
            float4 a = ps[h];
            afrag[ks][h * 4 + 0] = (short)f2bf(a.x);
            afrag[ks][h * 4 + 1] = (short)f2bf(a.y);
            afrag[ks][h * 4 + 2] = (short)f2bf(a.z);
            afrag[ks][h * 4 + 3] = (short)f2bf(a.w);
        }
    }

    // ---- Phase B: MFMA, B double-buffered in LDS ----
    f32x4 acc[NNT];
    #pragma unroll
    for (int nt = 0; nt < NNT; ++nt) acc[nt] = (f32x4)(0.f);

    #pragma unroll
    for (int u = 0; u < 4; ++u) Bls[0][tid + 256 * u] = Bbuf[tid + 256 * u];
    __syncthreads();

    #pragma unroll
    for (int ks = 0; ks < NKS; ++ks) {
        const int cur = ks & 1;
        uint4 st[4];
        if (ks < NKS - 1) {
            #pragma unroll
            for (int u = 0; u < 4; ++u)
                st[u] = Bbuf[(size_t)(ks + 1) * 1024 + tid + 256 * u];
        }
        #pragma unroll
        for (int nt = 0; nt < NNT; ++nt) {
            bf16x8 bfr = *reinterpret_cast<const bf16x8*>(&Bls[cur][nt * 64 + lane]);
            acc[nt] = __builtin_amdgcn_mfma_f32_16x16x32_bf16(afrag[ks], bfr, acc[nt], 0, 0, 0);
        }
        if (ks < NKS - 1) {
            #pragma unroll
            for (int u = 0; u < 4; ++u) Bls[cur ^ 1][tid + 256 * u] = st[u];
        }
        __syncthreads();
    }

    // ---- epilogue: +bias (h in registers), per-block column stats ----
    const int col16 = lane & 15, rg = lane >> 4;
    float s_[NNT], q_[NNT];
    #pragma unroll
    for (int nt = 0; nt < NNT; ++nt) {
        float bn = b1[nt * 16 + col16];
        float s = 0.f, q = 0.f;
        #pragma unroll
        for (int r = 0; r < 4; ++r) {
            acc[nt][r] += bn;
            s += acc[nt][r];
            q += acc[nt][r] * acc[nt][r];
        }
        s += __shfl_xor(s, 16); s += __shfl_xor(s, 32);
        q += __shfl_xor(q, 16); q += __shfl_xor(q, 32);
        s_[nt] = s; q_[nt] = q;
    }
    float* S = reinterpret_cast<float*>(&Bls[0][0]);
    if (lane < 16) {
        #pragma unroll
        for (int nt = 0; nt < NNT; ++nt) {
            S[wave * 256 + nt * 16 + lane]        = s_[nt];
            S[1024 + wave * 256 + nt * 16 + lane] = q_[nt];
        }
    }
    __syncthreads();
    {
        float s = S[tid] + S[256 + tid] + S[512 + tid] + S[768 + tid];
        float q = S[1024 + tid] + S[1280 + tid] + S[1536 + tid] + S[1792 + tid];
        // transposed layout [channel][block] so phase C reads coalesced
        psum_t[(size_t)tid * 256 + blk] = s;
        psq_t [(size_t)tid * 256 + blk] = q;
    }
    __threadfence();
    grid.sync();
    __threadfence();

    // ---- Phase C: block blk reduces channel blk ----
    {
        float s = psum_t[(size_t)blk * 256 + tid];
        float q = psq_t [(size_t)blk * 256 + tid];
        #pragma unroll
        for (int off = 32; off; off >>= 1) {
            s += __shfl_xor(s, off);
            q += __shfl_xor(q, off);
        }
        if (lane == 0) { cred[wave] = s; cred[8 + wave] = q; }
        __syncthreads();
        if (tid == 0) {
            float Sv = (cred[0] + cred[1]) + (cred[2] + cred[3]);
            float Qv = (cred[8] + cred[9]) + (cred[10] + cred[11]);
            float mean = Sv / NYF;
            float var  = Qv / NYF - mean * mean;
            float rstd = rsqrtf(var + 1e-6f);
            float sc = gamma[blk] * rstd;
            sscale[blk]       = sc;
            sscale[256 + blk] = beta[blk] - mean * sc;
        }
    }
    __threadfence();
    grid.sync();
    __threadfence();

    // ---- Phase D: BN apply + LeakyReLU on registers -> single write; tail ----
    const int rowb = blk * 64 + wave * 16 + rg * 4;
    #pragma unroll
    for (int nt = 0; nt < NNT; ++nt) {
        int ch = nt * 16 + col16;
        float sc = sscale[ch];
        float sh = sscale[256 + ch];
        #pragma unroll
        for (int r = 0; r < 4; ++r) {
            float v = acc[nt][r] * sc + sh;
            v = v > 0.f ? v : 0.2f * v;
            outp[(size_t)(rowb + r) * CO + ch] = v;
        }
    }
    int gid = blk * 256 + tid;
    float4* ot = reinterpret_cast<float4*>(outp + (size_t)16384 * CO);
    if (gid < NPOS4) {
        ot[gid] = pos_skip4[gid];
    } else if (gid < NTAIL4) {
        int4 b4 = batch4[gid - NPOS4];
        ot[gid] = make_float4((float)b4.x, (float)b4.y, (float)b4.z, (float)b4.w);
    }
}

extern "C" void kernel_launch(void* const* d_in, const int* in_sizes, int n_in,
                              void* d_out, int out_size, void* d_ws, size_t ws_size,
                              hipStream_t stream) {
    const float* x         = (const float*)d_in[0];
    const float* pos       = (const float*)d_in[1];
    const int*   batch     = (const int*)d_in[2];
    const float* x_skip    = (const float*)d_in[3];
    const float* pos_skip  = (const float*)d_in[4];
    const int*   batch_skip= (const int*)d_in[5];
    const float* w_att     = (const float*)d_in[6];
    const float* W1        = (const float*)d_in[7];
    const float* b1        = (const float*)d_in[8];
    const float* gamma     = (const float*)d_in[9];
    const float* beta      = (const float*)d_in[10];

    const int Nx = in_sizes[2];      // 4096
    const int Ny = in_sizes[5];      // 16384
    const int NB = 8;

    char* w = (char*)d_ws;
    uint4*  Bbuf     = (uint4*)w;  w += (size_t)NKS * NNT * 64 * 16;      // 196 KB
    float4* pos4     = (float4*)w; w += (size_t)(Nx + 64) * 16;
    float*  attv     = (float*)w;  w += (size_t)Nx * 4;
    int*    knn_idx  = (int*)w;    w += (size_t)Ny * 3 * 4;
    float*  knn_coef = (float*)w;  w += (size_t)Ny * 3 * 4;
    float*  psum_t   = (float*)w;  w += (size_t)256 * 256 * 4;
    float*  psq_t    = (float*)w;  w += (size_t)256 * 256 * 4;
    float*  sscale   = (float*)w;  w += (size_t)512 * 4;
    int*    start    = (int*)w;    w += 64;

    float* outp = (float*)d_out;
    const float4* pos_skip4 = (const float4*)pos_skip;
    const int4*   batch4    = (const int4*)batch_skip;

    k_prep<<<dim3(Nx / 4 + 48 + 1), dim3(256), 0, stream>>>(
        x, pos, w_att, W1, batch, attv, pos4, Bbuf, start, Nx, NB);
    k_knn<<<dim3(Ny * GL / 256), dim3(256), 0, stream>>>(
        pos4, attv, pos_skip, batch_skip, start, knn_idx, knn_coef, Ny);

    void* args[] = {
        (void*)&x, (void*)&x_skip, (void*)&Bbuf, (void*)&b1,
        (void*)&knn_idx, (void*)&knn_coef, (void*)&gamma, (void*)&beta,
        (void*)&outp, (void*)&psum_t, (void*)&psq_t, (void*)&sscale,
        (void*)&pos_skip4, (void*)&batch4
    };
    hipLaunchCooperativeKernel((void*)k_coop, dim3(256), dim3(256), args, 0, stream);
}

// Round 7
// 100.200 us; speedup vs baseline: 2.0216x; 2.0216x over previous
//
#include <hip/hip_runtime.h>
#include <math.h>

// ---------------------------------------------------------------------------
// AttentiveFPModule: knn(K=3) attentive interpolate + concat + Linear + BN + LeakyReLU
// Sizes: Nx=4096, Ny=16384, C=256, Cs=128, Co=256, B=4, Kin=384
// 4 launches: k_prep (attv/pos4/Bbuf/start/tail/counter) -> k_knn (LDS-staged)
//             -> k_gemm (reg-gather + MFMA + h + last-block BN stats)
//             -> k_final (BN apply, in place).
// ---------------------------------------------------------------------------

#define KNEI 3
#define GL 16           // lanes per y-point in k_knn
#define UNR 4           // scan unroll
#define KCAP 2048       // staged pos4 capacity (float4s)
#define CIN 256         // C
#define CSK 128         // Cs
#define CO  256         // Co
#define NKS 12          // Kin / 32
#define NNT 16          // Co / 16
#define NYF 16384.0f
#define NPOS4 12288     // Ny*3/4
#define NTAIL4 16384    // NPOS4 + Ny/4

typedef __attribute__((ext_vector_type(8))) short bf16x8;
typedef __attribute__((ext_vector_type(4))) float f32x4;

__device__ __forceinline__ ushort f2bf(float f) {
    unsigned u = __float_as_uint(f);
    u += 0x7fffu + ((u >> 16) & 1u);
    return (ushort)(u >> 16);
}

__device__ __forceinline__ bool nless(float da, int ia, float db, int ib) {
    return (da < db) || (da == db && ia < ib);
}

__device__ __forceinline__ void ins3f(float dd, int j,
                                      float& d0, int& i0,
                                      float& d1, int& i1,
                                      float& d2, int& i2) {
    bool l0 = dd < d0;
    bool l1 = dd < d1;
    bool l2 = dd < d2;
    float n2 = l1 ? d1 : (l2 ? dd : d2); int m2 = l1 ? i1 : (l2 ? j : i2);
    float n1 = l0 ? d0 : (l1 ? dd : d1); int m1 = l0 ? i0 : (l1 ? j : i1);
    float n0 = l0 ? dd : d0;             int m0 = l0 ? j  : i0;
    d0 = n0; i0 = m0; d1 = n1; i1 = m1; d2 = n2; i2 = m2;
}

__device__ __forceinline__ void ins3t(float dd, int j,
                                      float& d0, int& i0,
                                      float& d1, int& i1,
                                      float& d2, int& i2) {
    bool l0 = nless(dd, j, d0, i0);
    bool l1 = nless(dd, j, d1, i1);
    bool l2 = nless(dd, j, d2, i2);
    float n2 = l1 ? d1 : (l2 ? dd : d2); int m2 = l1 ? i1 : (l2 ? j : i2);
    float n1 = l0 ? d0 : (l1 ? dd : d1); int m1 = l0 ? i0 : (l1 ? j : i1);
    float n0 = l0 ? dd : d0;             int m0 = l0 ? j  : i0;
    d0 = n0; i0 = m0; d1 = n1; i1 = m1; d2 = n2; i2 = m2;
}

// K1 (multi-role by block range):
//   [0, Nx/4)            : attv[j] = x[j].w_att ; pos4[j] = (pos, |pos|^2)
//   [Nx/4, Nx/4+48)      : W1 -> Bbuf MFMA B-fragments (bf16)
//   Nx/4+48              : start[] lower bounds; pos4 pad; counter = 0
//   [Nx/4+49, +49+64)    : tail outputs (pos_skip copy, batch_skip as float)
__global__ void k_prep(const float* __restrict__ x, const float* __restrict__ pos,
                       const float* __restrict__ w_att, const float* __restrict__ W1,
                       const int* __restrict__ batch,
                       float* __restrict__ attv, float4* __restrict__ pos4,
                       uint4* __restrict__ Bbuf, int* __restrict__ start,
                       int* __restrict__ counter,
                       const float4* __restrict__ pos_skip4,
                       const int4* __restrict__ batch4,
                       float4* __restrict__ out_tail4,
                       int Nx, int NB) {
    int nb_x = Nx >> 2;
    int bid = blockIdx.x;
    int wave = threadIdx.x >> 6;
    int lane = threadIdx.x & 63;

    if (bid < nb_x) {
        int wid = bid * 4 + wave;
        float s = 0.f;
        for (int k = lane * 4; k < CIN; k += 256) {
            float4 xv = *reinterpret_cast<const float4*>(x + (size_t)wid * CIN + k);
            float4 wv = *reinterpret_cast<const float4*>(w_att + k);
            s += xv.x * wv.x + xv.y * wv.y + xv.z * wv.z + xv.w * wv.w;
        }
        #pragma unroll
        for (int off = 32; off; off >>= 1) s += __shfl_xor(s, off);
        if (lane == 0) {
            attv[wid] = s;
            float px = pos[wid * 3], py = pos[wid * 3 + 1], pz = pos[wid * 3 + 2];
            pos4[wid] = make_float4(px, py, pz, px * px + py * py + pz * pz);
        }
        return;
    }
    if (bid < nb_x + 48) {
        // Bbuf[(ks*16+nt)*64 + lane] = 8 bf16: elem j = W1[ks*32+(lane>>4)*8+j][nt*16+(lane&15)]
        int p  = (bid - nb_x) * 4 + wave;      // 0..191
        int ks = p >> 4, nt = p & 15;
        int kb = ks * 32 + (lane >> 4) * 8;
        int n  = nt * 16 + (lane & 15);
        ushort u[8];
        #pragma unroll
        for (int j = 0; j < 8; ++j)
            u[j] = f2bf(W1[(size_t)(kb + j) * CO + n]);
        uint4 o;
        o.x = (unsigned)u[0] | ((unsigned)u[1] << 16);
        o.y = (unsigned)u[2] | ((unsigned)u[3] << 16);
        o.z = (unsigned)u[4] | ((unsigned)u[5] << 16);
        o.w = (unsigned)u[6] | ((unsigned)u[7] << 16);
        Bbuf[(size_t)(ks * 16 + nt) * 64 + lane] = o;
        return;
    }
    if (bid == nb_x + 48) {
        int t = threadIdx.x;
        if (t < 64) {
            int b = t;
            if (b > NB) return;
            int lo = 0, hi = Nx;
            while (lo < hi) {
                int mid = (lo + hi) >> 1;
                if (batch[mid] < b) lo = mid + 1; else hi = mid;
            }
            start[b] = lo;
        } else if (t < 128) {
            pos4[Nx + (t - 64)] = make_float4(0.f, 0.f, 0.f, 0.f);
        } else if (t == 128) {
            *counter = 0;
        }
        return;
    }
    // tail outputs
    int gid = (bid - (nb_x + 49)) * 256 + threadIdx.x;
    if (gid < NPOS4) {
        out_tail4[gid] = pos_skip4[gid];
    } else if (gid < NTAIL4) {
        int4 b4 = batch4[gid - NPOS4];
        out_tail4[gid] = make_float4((float)b4.x, (float)b4.y, (float)b4.z, (float)b4.w);
    }
}

// K2: 16 y-points per block (16 lanes each). Batch's pos4 segment staged in
// LDS when it fits (all single-batch blocks); global fallback otherwise.
__global__ __launch_bounds__(256) void k_knn(
                      const float4* __restrict__ pos4,
                      const float* __restrict__ attv,
                      const float* __restrict__ pos_skip,
                      const int* __restrict__ batch_skip,
                      const int* __restrict__ start,
                      int* __restrict__ knn_idx, float* __restrict__ knn_coef,
                      int Ny) {
    __shared__ float4 seg[KCAP + 64];
    int i   = blockIdx.x * 16 + (threadIdx.x >> 4);
    int sub = threadIdx.x & (GL - 1);

    float py0 = pos_skip[i * 3], py1 = pos_skip[i * 3 + 1], py2 = pos_skip[i * 3 + 2];
    int bb = batch_skip[i];
    int s = start[bb], e = start[bb + 1];
    float ysq = py0 * py0 + py1 * py1 + py2 * py2;

    // block-uniform staging decision
    int b_first = batch_skip[blockIdx.x * 16];
    int b_last  = batch_skip[blockIdx.x * 16 + 15];
    int s0 = start[b_first];
    int span = start[b_last + 1] - s0;
    bool staged = (span <= KCAP);
    if (staged) {
        for (int t = threadIdx.x; t < span; t += 256) seg[t] = pos4[s0 + t];
        __syncthreads();
    }

    const float FBIG = 3.38e38f;
    float a0 = __int_as_float(0x7f800000), a1 = a0, a2 = a0;
    float b0 = a0, b1v = a0, b2 = a0;
    int   ia0 = 0x7fffffff, ia1 = 0x7fffffff, ia2 = 0x7fffffff;
    int   ib0 = 0x7fffffff, ib1 = 0x7fffffff, ib2 = 0x7fffffff;

    if (staged) {
        for (int jb = s + sub; jb < e; jb += GL * UNR) {
            int j0 = jb, j1 = jb + GL, j2 = jb + 2 * GL, j3 = jb + 3 * GL;
            float4 v0 = seg[j0 - s0];
            float4 v1 = seg[j1 - s0];
            float4 v2 = seg[j2 - s0];
            float4 v3 = seg[j3 - s0];
            float t0 = fmaf(py2, v0.z, fmaf(py1, v0.y, py0 * v0.x));
            float t1 = fmaf(py2, v1.z, fmaf(py1, v1.y, py0 * v1.x));
            float t2 = fmaf(py2, v2.z, fmaf(py1, v2.y, py0 * v2.x));
            float t3 = fmaf(py2, v3.z, fmaf(py1, v3.y, py0 * v3.x));
            float dd0 = fmaf(-2.f, t0, ysq + v0.w);
            float dd1 = fmaf(-2.f, t1, ysq + v1.w);
            float dd2 = fmaf(-2.f, t2, ysq + v2.w);
            float dd3 = fmaf(-2.f, t3, ysq + v3.w);
            dd1 = (j1 < e) ? dd1 : FBIG;
            dd2 = (j2 < e) ? dd2 : FBIG;
            dd3 = (j3 < e) ? dd3 : FBIG;
            ins3f(dd0, j0, a0, ia0, a1, ia1, a2, ia2);
            ins3f(dd1, j1, b0, ib0, b1v, ib1, b2, ib2);
            ins3f(dd2, j2, a0, ia0, a1, ia1, a2, ia2);
            ins3f(dd3, j3, b0, ib0, b1v, ib1, b2, ib2);
        }
    } else {
        for (int jb = s + sub; jb < e; jb += GL * UNR) {
            int j0 = jb, j1 = jb + GL, j2 = jb + 2 * GL, j3 = jb + 3 * GL;
            float4 v0 = pos4[j0];
            float4 v1 = pos4[j1];
            float4 v2 = pos4[j2];
            float4 v3 = pos4[j3];
            float t0 = fmaf(py2, v0.z, fmaf(py1, v0.y, py0 * v0.x));
            float t1 = fmaf(py2, v1.z, fmaf(py1, v1.y, py0 * v1.x));
            float t2 = fmaf(py2, v2.z, fmaf(py1, v2.y, py0 * v2.x));
            float t3 = fmaf(py2, v3.z, fmaf(py1, v3.y, py0 * v3.x));
            float dd0 = fmaf(-2.f, t0, ysq + v0.w);
            float dd1 = fmaf(-2.f, t1, ysq + v1.w);
            float dd2 = fmaf(-2.f, t2, ysq + v2.w);
            float dd3 = fmaf(-2.f, t3, ysq + v3.w);
            dd1 = (j1 < e) ? dd1 : FBIG;
            dd2 = (j2 < e) ? dd2 : FBIG;
            dd3 = (j3 < e) ? dd3 : FBIG;
            ins3f(dd0, j0, a0, ia0, a1, ia1, a2, ia2);
            ins3f(dd1, j1, b0, ib0, b1v, ib1, b2, ib2);
            ins3f(dd2, j2, a0, ia0, a1, ia1, a2, ia2);
            ins3f(dd3, j3, b0, ib0, b1v, ib1, b2, ib2);
        }
    }

    ins3t(b0, ib0, a0, ia0, a1, ia1, a2, ia2);
    ins3t(b1v, ib1, a0, ia0, a1, ia1, a2, ia2);
    ins3t(b2, ib2, a0, ia0, a1, ia1, a2, ia2);

    #pragma unroll
    for (int off = 1; off < GL; off <<= 1) {
        float e0 = __shfl_xor(a0, off), e1 = __shfl_xor(a1, off), e2 = __shfl_xor(a2, off);
        int   j0 = __shfl_xor(ia0, off), j1 = __shfl_xor(ia1, off), j2 = __shfl_xor(ia2, off);
        ins3t(e0, j0, a0, ia0, a1, ia1, a2, ia2);
        ins3t(e1, j1, a0, ia0, a1, ia1, a2, ia2);
        ins3t(e2, j2, a0, ia0, a1, ia1, a2, ia2);
    }

    if (sub == 0) {
        int   jj[3] = { ia0, ia1, ia2 };
        float w[3], a[3];
        #pragma unroll
        for (int t = 0; t < KNEI; ++t) {
            int j = (jj[t] == 0x7fffffff) ? 0 : jj[t];
            jj[t] = j;
            float4 v = pos4[j];
            float dx = v.x - py0;
            float dy = v.y - py1;
            float dz = v.z - py2;
            float sqd = dx * dx + dy * dy + dz * dz;
            w[t] = 1.f / fmaxf(sqd, 1e-16f);
            a[t] = attv[j];
        }
        float m  = fmaxf(a[0], fmaxf(a[1], a[2]));
        float e0s = expf(a[0] - m), e1s = expf(a[1] - m), e2s = expf(a[2] - m);
        float se  = e0s + e1s + e2s;
        float den = w[0] + w[1] + w[2];
        float inv = 1.f / (se * den);
        float c[3] = { w[0] * e0s * inv, w[1] * e1s * inv, w[2] * e2s * inv };
        #pragma unroll
        for (int t = 0; t < KNEI; ++t) {
            knn_idx[i * 3 + t]  = jj[t];
            knn_coef[i * 3 + t] = c[t];
        }
    }
}

// K3: gather A=[y||x_skip] into register fragments -> MFMA -> h (f32, +bias)
// -> per-block BN partials; the 256th block to finish reduces partials into
// scale/shift (fence + atomic counter; deterministic fixed-order reduce).
__global__ __launch_bounds__(256) void k_gemm(
    const float* __restrict__ x, const float* __restrict__ x_skip,
    const uint4* __restrict__ Bbuf, const float* __restrict__ b1,
    const int* __restrict__ knn_idx, const float* __restrict__ knn_coef,
    const float* __restrict__ gamma, const float* __restrict__ beta,
    float* __restrict__ hbuf, float* __restrict__ psum, float* __restrict__ psq,
    float* __restrict__ sscale, int* __restrict__ counter) {
    __shared__ uint4 Bls[2][1024];   // 32 KB
    __shared__ float SQ[8][256];     // 8 KB (stats combine)
    __shared__ int lastFlag;
    const int tid = threadIdx.x;
    const int wave = tid >> 6, lane = tid & 63;
    const int blk = blockIdx.x;

    // ---- Phase A: gather A-fragments into registers ----
    const int row16 = lane & 15, kg = lane >> 4;
    const int i = blk * 64 + wave * 16 + row16;
    const int gi0 = knn_idx[i * 3 + 0];
    const int gi1 = knn_idx[i * 3 + 1];
    const int gi2 = knn_idx[i * 3 + 2];
    const float c0 = knn_coef[i * 3 + 0];
    const float c1 = knn_coef[i * 3 + 1];
    const float c2 = knn_coef[i * 3 + 2];

    bf16x8 afrag[NKS];
    #pragma unroll
    for (int ks = 0; ks < 8; ++ks) {
        const int k0 = ks * 32 + kg * 8;
        const float4* p0 = reinterpret_cast<const float4*>(x + (size_t)gi0 * CIN + k0);
        const float4* p1 = reinterpret_cast<const float4*>(x + (size_t)gi1 * CIN + k0);
        const float4* p2 = reinterpret_cast<const float4*>(x + (size_t)gi2 * CIN + k0);
        #pragma unroll
        for (int h = 0; h < 2; ++h) {
            float4 a = p0[h], b = p1[h], c = p2[h];
            afrag[ks][h * 4 + 0] = (short)f2bf(c0 * a.x + c1 * b.x + c2 * c.x);
            afrag[ks][h * 4 + 1] = (short)f2bf(c0 * a.y + c1 * b.y + c2 * c.y);
            afrag[ks][h * 4 + 2] = (short)f2bf(c0 * a.z + c1 * b.z + c2 * c.z);
            afrag[ks][h * 4 + 3] = (short)f2bf(c0 * a.w + c1 * b.w + c2 * c.w);
        }
    }
    #pragma unroll
    for (int ks = 8; ks < NKS; ++ks) {
        const int k0 = (ks - 8) * 32 + kg * 8;
        const float4* ps = reinterpret_cast<const float4*>(x_skip + (size_t)i * CSK + k0);
        #pragma unroll
        for (int h = 0; h < 2; ++h) {
            float4 a = ps[h];
            afrag[ks][h * 4 + 0] = (short)f2bf(a.x);
            afrag[ks][h * 4 + 1] = (short)f2bf(a.y);
            afrag[ks][h * 4 + 2] = (short)f2bf(a.z);
            afrag[ks][h * 4 + 3] = (short)f2bf(a.w);
        }
    }

    // ---- Phase B: MFMA, B double-buffered in LDS ----
    f32x4 acc[NNT];
    #pragma unroll
    for (int nt = 0; nt < NNT; ++nt) acc[nt] = (f32x4)(0.f);

    #pragma unroll
    for (int u = 0; u < 4; ++u) Bls[0][tid + 256 * u] = Bbuf[tid + 256 * u];
    __syncthreads();

    #pragma unroll
    for (int ks = 0; ks < NKS; ++ks) {
        const int cur = ks & 1;
        uint4 st[4];
        if (ks < NKS - 1) {
            #pragma unroll
            for (int u = 0; u < 4; ++u)
                st[u] = Bbuf[(size_t)(ks + 1) * 1024 + tid + 256 * u];
        }
        #pragma unroll
        for (int nt = 0; nt < NNT; ++nt) {
            bf16x8 bfr = *reinterpret_cast<const bf16x8*>(&Bls[cur][nt * 64 + lane]);
            acc[nt] = __builtin_amdgcn_mfma_f32_16x16x32_bf16(afrag[ks], bfr, acc[nt], 0, 0, 0);
        }
        if (ks < NKS - 1) {
            #pragma unroll
            for (int u = 0; u < 4; ++u) Bls[cur ^ 1][tid + 256 * u] = st[u];
        }
        __syncthreads();
    }

    // ---- epilogue: +bias, write h (f32), per-block column stats ----
    const int col16 = lane & 15, rg = lane >> 4;
    const int rowb = blk * 64 + wave * 16 + rg * 4;
    float s_[NNT], q_[NNT];
    #pragma unroll
    for (int nt = 0; nt < NNT; ++nt) {
        float bn = b1[nt * 16 + col16];
        float s = 0.f, q = 0.f;
        #pragma unroll
        for (int r = 0; r < 4; ++r) {
            acc[nt][r] += bn;
            hbuf[(size_t)(rowb + r) * CO + nt * 16 + col16] = acc[nt][r];
            s += acc[nt][r];
            q += acc[nt][r] * acc[nt][r];
        }
        s += __shfl_xor(s, 16); s += __shfl_xor(s, 32);
        q += __shfl_xor(q, 16); q += __shfl_xor(q, 32);
        s_[nt] = s; q_[nt] = q;
    }
    float* S = reinterpret_cast<float*>(&Bls[0][0]);
    if (lane < 16) {
        #pragma unroll
        for (int nt = 0; nt < NNT; ++nt) {
            S[wave * 256 + nt * 16 + lane]        = s_[nt];
            S[1024 + wave * 256 + nt * 16 + lane] = q_[nt];
        }
    }
    __syncthreads();
    {
        float s = S[tid] + S[256 + tid] + S[512 + tid] + S[768 + tid];
        float q = S[1024 + tid] + S[1280 + tid] + S[1536 + tid] + S[1792 + tid];
        psum[(size_t)blk * CO + tid] = s;   // [block][channel], coalesced
        psq [(size_t)blk * CO + tid] = q;
    }
    __threadfence();
    if (tid == 0) lastFlag = (atomicAdd(counter, 1) == 255);
    __syncthreads();
    if (!lastFlag) return;
    __threadfence();   // acquire: all blocks' partials now visible

    // ---- last block: reduce partials -> scale/shift ----
    f32x4 sv = (f32x4)(0.f), qv = (f32x4)(0.f);
    for (int b = wave * 64; b < wave * 64 + 64; ++b) {
        float4 s4 = *reinterpret_cast<const float4*>(psum + (size_t)b * CO + lane * 4);
        float4 q4 = *reinterpret_cast<const float4*>(psq  + (size_t)b * CO + lane * 4);
        sv.x += s4.x; sv.y += s4.y; sv.z += s4.z; sv.w += s4.w;
        qv.x += q4.x; qv.y += q4.y; qv.z += q4.z; qv.w += q4.w;
    }
    #pragma unroll
    for (int u = 0; u < 4; ++u) {
        SQ[wave][lane * 4 + u]     = sv[u];
        SQ[4 + wave][lane * 4 + u] = qv[u];
    }
    __syncthreads();
    {
        float Sv = (SQ[0][tid] + SQ[1][tid]) + (SQ[2][tid] + SQ[3][tid]);
        float Qv = (SQ[4][tid] + SQ[5][tid]) + (SQ[6][tid] + SQ[7][tid]);
        float mean = Sv / NYF;
        float var  = Qv / NYF - mean * mean;
        float rstd = rsqrtf(var + 1e-6f);
        float sc = gamma[tid] * rstd;
        sscale[tid]       = sc;
        sscale[256 + tid] = beta[tid] - mean * sc;
    }
}

// K4: BN apply + LeakyReLU over h, in place (float4, grid-stride).
__global__ void k_final(float* __restrict__ h, const float* __restrict__ sscale,
                        int total4) {
    for (int t = blockIdx.x * blockDim.x + threadIdx.x; t < total4;
         t += gridDim.x * blockDim.x) {
        int c4 = (t & (CO / 4 - 1)) * 4;
        float4 v  = *reinterpret_cast<float4*>(h + (size_t)t * 4);
        float4 sc = *reinterpret_cast<const float4*>(sscale + c4);
        float4 sh = *reinterpret_cast<const float4*>(sscale + 256 + c4);
        v.x = v.x * sc.x + sh.x; v.x = v.x > 0.f ? v.x : 0.2f * v.x;
        v.y = v.y * sc.y + sh.y; v.y = v.y > 0.f ? v.y : 0.2f * v.y;
        v.z = v.z * sc.z + sh.z; v.z = v.z > 0.f ? v.z : 0.2f * v.z;
        v.w = v.w * sc.w + sh.w; v.w = v.w > 0.f ? v.w : 0.2f * v.w;
        *reinterpret_cast<float4*>(h + (size_t)t * 4) = v;
    }
}

extern "C" void kernel_launch(void* const* d_in, const int* in_sizes, int n_in,
                              void* d_out, int out_size, void* d_ws, size_t ws_size,
                              hipStream_t stream) {
    const float* x         = (const float*)d_in[0];
    const float* pos       = (const float*)d_in[1];
    const int*   batch     = (const int*)d_in[2];
    const float* x_skip    = (const float*)d_in[3];
    const float* pos_skip  = (const float*)d_in[4];
    const int*   batch_skip= (const int*)d_in[5];
    const float* w_att     = (const float*)d_in[6];
    const float* W1        = (const float*)d_in[7];
    const float* b1        = (const float*)d_in[8];
    const float* gamma     = (const float*)d_in[9];
    const float* beta      = (const float*)d_in[10];

    const int Nx = in_sizes[2];      // 4096
    const int Ny = in_sizes[5];      // 16384
    const int NB = 8;

    char* w = (char*)d_ws;
    uint4*  Bbuf     = (uint4*)w;  w += (size_t)NKS * NNT * 64 * 16;      // 196 KB
    float4* pos4     = (float4*)w; w += (size_t)(Nx + 64) * 16;
    float*  attv     = (float*)w;  w += (size_t)Nx * 4;
    int*    knn_idx  = (int*)w;    w += (size_t)Ny * 3 * 4;
    float*  knn_coef = (float*)w;  w += (size_t)Ny * 3 * 4;
    float*  psum     = (float*)w;  w += (size_t)256 * CO * 4;
    float*  psq      = (float*)w;  w += (size_t)256 * CO * 4;
    float*  sscale   = (float*)w;  w += (size_t)512 * 4;
    int*    counter  = (int*)w;    w += 64;
    int*    start    = (int*)w;    w += 64;

    float* outp = (float*)d_out;
    float* hbuf = outp;                                   // [Ny][Co] f32
    float4* out_tail4 = (float4*)(outp + (size_t)Ny * CO);
    const float4* pos_skip4 = (const float4*)pos_skip;
    const int4*   batch4    = (const int4*)batch_skip;

    const int total4 = Ny * CO / 4;

    k_prep<<<dim3(Nx / 4 + 49 + 64), dim3(256), 0, stream>>>(
        x, pos, w_att, W1, batch, attv, pos4, Bbuf, start, counter,
        pos_skip4, batch4, out_tail4, Nx, NB);
    k_knn<<<dim3(Ny / 16), dim3(256), 0, stream>>>(
        pos4, attv, pos_skip, batch_skip, start, knn_idx, knn_coef, Ny);
    k_gemm<<<dim3(Ny / 64), dim3(256), 0, stream>>>(
        x, x_skip, Bbuf, b1, knn_idx, knn_coef, gamma, beta,
        hbuf, psum, psq, sscale, counter);
    k_final<<<dim3(2048), dim3(256), 0, stream>>>(hbuf, sscale, total4);
}